// Round 10
// baseline (147095.728 us; speedup 1.0000x reference)
//
#include <hip/hip_runtime.h>
#include <math.h>

#define BATCH 64
#define TSTEPS 1200
#define DIN 3
#define U 400
#define G 1600   // 4*U
#define MOUT 121

// scan16 geometry
#define NGROUP 16   // batch groups
#define BW 4        // batches per group
#define NSLICE 16   // unit slices per group
#define UPS 25      // units per slice
#define HPAD 408    // h_lds row pad (words): bi*408%32={0,24,16,8}; kh offset
                    // 100%32=4 -> mixed waves cover all 32 banks once.

// ---------------------------------------------------------------------------
// Pack Wh [400][1600] -> WP[s][gate][kh][j][ul] float4 (j = k-quarter-local k4)
// ---------------------------------------------------------------------------
__global__ __launch_bounds__(256) void pack_w16(const float* __restrict__ Wh,
                                                float* __restrict__ WP) {
  const int idx = blockIdx.x * blockDim.x + threadIdx.x;  // (s,gate,kh,j,ul)
  if (idx >= 160000) return;
  const int ul   = idx % 25;
  const int j    = (idx / 25) % 25;
  const int kh   = (idx / 625) % 4;
  const int gate = (idx / 2500) % 4;
  const int s    = idx / 10000;
  const int k4 = kh * 25 + j;
  const int col = gate * 400 + s * UPS + ul;
  float4 v;
  v.x = Wh[(size_t)(k4 * 4 + 0) * G + col];
  v.y = Wh[(size_t)(k4 * 4 + 1) * G + col];
  v.z = Wh[(size_t)(k4 * 4 + 2) * G + col];
  v.w = Wh[(size_t)(k4 * 4 + 3) * G + col];
  *(float4*)&WP[(size_t)idx * 4] = v;
}

// ---------------------------------------------------------------------------
// zx0 chunk: zx[btl][n] = b0[n] + sum_d x[g(btl)][d] * Wx0[d][n]
// chunk-local row btl -> global (b = btl/tcnt, t = t0 + btl%tcnt).
// ---------------------------------------------------------------------------
__global__ __launch_bounds__(256) void zx0_kernel(const float* __restrict__ x,
                                                  const float* __restrict__ Wx0,
                                                  const float* __restrict__ b0,
                                                  float* __restrict__ zx,
                                                  int t0, int tcnt) {
  const int total = BATCH * tcnt * (G / 4);
  for (int idx = blockIdx.x * blockDim.x + threadIdx.x; idx < total;
       idx += gridDim.x * blockDim.x) {
    const int btl = idx / (G / 4);
    const int n4 = idx % (G / 4);
    const int b = btl / tcnt;
    const int tt = btl % tcnt;
    const size_t gbt = (size_t)b * TSTEPS + t0 + tt;
    const float x0 = x[gbt * 3 + 0];
    const float x1 = x[gbt * 3 + 1];
    const float x2 = x[gbt * 3 + 2];
    const float4 w0 = *(const float4*)&Wx0[0 * G + n4 * 4];
    const float4 w1 = *(const float4*)&Wx0[1 * G + n4 * 4];
    const float4 w2 = *(const float4*)&Wx0[2 * G + n4 * 4];
    const float4 bb = *(const float4*)&b0[n4 * 4];
    float4 r;
    r.x = bb.x + x0 * w0.x + x1 * w1.x + x2 * w2.x;
    r.y = bb.y + x0 * w0.y + x1 * w1.y + x2 * w2.y;
    r.z = bb.z + x0 * w0.z + x1 * w1.z + x2 * w2.z;
    r.w = bb.w + x0 * w0.w + x1 * w1.w + x2 * w2.w;
    *(float4*)&zx[(size_t)idx * 4] = r;
  }
}

// ---------------------------------------------------------------------------
// zx for layers 1/2, chunked. BM=128, BN=64, BK=16, block 256, 8x4/thread.
// hprev is the CHUNK-LOCAL h buffer [B*tcnt][400] (row = b*tcnt+tt);
// x rows mapped to global (b,t); out chunk-local. grid (25, 64*tcnt/128).
// ---------------------------------------------------------------------------
__global__ __launch_bounds__(256) void zx_gemm2(const float* __restrict__ hprev, // [B*tcnt][400] chunk
                                                const float* __restrict__ x,     // [B*T][3] global
                                                const float* __restrict__ Wx,    // [403][1600]
                                                const float* __restrict__ bias,  // [1600]
                                                float* __restrict__ out,         // [B*tcnt][1600] chunk
                                                int t0, int tcnt) {
  __shared__ float As[16][136];  // As[k][m]
  __shared__ float Bs[16][64];   // Bs[k][n]
  const int n0 = blockIdx.x * 64;
  const int m0 = blockIdx.y * 128;
  const int tid = threadIdx.x;
  const int tx = tid & 15;   // n group (4 cols)
  const int ty = tid >> 4;   // m group (8 rows)
  float acc[8][4];
#pragma unroll
  for (int i = 0; i < 8; ++i)
#pragma unroll
    for (int j = 0; j < 4; ++j) acc[i][j] = 0.f;

  const float* __restrict__ Wh_part = Wx + 3 * G;
  const int mlA = m0 + (tid >> 1);  // chunk-local row for A staging

  for (int k0 = 0; k0 < U; k0 += 16) {
    {  // stage A: 128 m x 16 k, 2 threads/row, 8 k-floats each, transpose
      const int kb = (tid & 1) * 8;
      const int m = tid >> 1;
      const float4 a0 = *(const float4*)&hprev[(size_t)mlA * U + k0 + kb];
      const float4 a1 = *(const float4*)&hprev[(size_t)mlA * U + k0 + kb + 4];
      As[kb + 0][m] = a0.x; As[kb + 1][m] = a0.y; As[kb + 2][m] = a0.z; As[kb + 3][m] = a0.w;
      As[kb + 4][m] = a1.x; As[kb + 5][m] = a1.y; As[kb + 6][m] = a1.z; As[kb + 7][m] = a1.w;
    }
    {  // stage B: 16 k x 64 n
      const int kk = tid >> 4;
      const int nn = (tid & 15) * 4;
      *(float4*)&Bs[kk][nn] = *(const float4*)&Wh_part[(size_t)(k0 + kk) * G + n0 + nn];
    }
    __syncthreads();
#pragma unroll
    for (int kk = 0; kk < 16; ++kk) {
      const float4 a0 = *(const float4*)&As[kk][ty * 8];
      const float4 a1 = *(const float4*)&As[kk][ty * 8 + 4];
      const float4 b4 = *(const float4*)&Bs[kk][tx * 4];
      acc[0][0] += a0.x * b4.x; acc[0][1] += a0.x * b4.y; acc[0][2] += a0.x * b4.z; acc[0][3] += a0.x * b4.w;
      acc[1][0] += a0.y * b4.x; acc[1][1] += a0.y * b4.y; acc[1][2] += a0.y * b4.z; acc[1][3] += a0.y * b4.w;
      acc[2][0] += a0.z * b4.x; acc[2][1] += a0.z * b4.y; acc[2][2] += a0.z * b4.z; acc[2][3] += a0.z * b4.w;
      acc[3][0] += a0.w * b4.x; acc[3][1] += a0.w * b4.y; acc[3][2] += a0.w * b4.z; acc[3][3] += a0.w * b4.w;
      acc[4][0] += a1.x * b4.x; acc[4][1] += a1.x * b4.y; acc[4][2] += a1.x * b4.z; acc[4][3] += a1.x * b4.w;
      acc[5][0] += a1.y * b4.x; acc[5][1] += a1.y * b4.y; acc[5][2] += a1.y * b4.z; acc[5][3] += a1.y * b4.w;
      acc[6][0] += a1.z * b4.x; acc[6][1] += a1.z * b4.y; acc[6][2] += a1.z * b4.z; acc[6][3] += a1.z * b4.w;
      acc[7][0] += a1.w * b4.x; acc[7][1] += a1.w * b4.y; acc[7][2] += a1.w * b4.z; acc[7][3] += a1.w * b4.w;
    }
    __syncthreads();
  }

  const int nbase = n0 + tx * 4;
  const float4 bb = *(const float4*)&bias[nbase];
  const float4 wd0 = *(const float4*)&Wx[0 * G + nbase];
  const float4 wd1 = *(const float4*)&Wx[1 * G + nbase];
  const float4 wd2 = *(const float4*)&Wx[2 * G + nbase];
#pragma unroll
  for (int i = 0; i < 8; ++i) {
    const int ml = m0 + ty * 8 + i;
    const size_t grow = (size_t)(ml / tcnt) * TSTEPS + t0 + (ml % tcnt);
    const float x0 = x[grow * 3 + 0];
    const float x1 = x[grow * 3 + 1];
    const float x2 = x[grow * 3 + 2];
    float4 r;
    r.x = acc[i][0] + bb.x + x0 * wd0.x + x1 * wd1.x + x2 * wd2.x;
    r.y = acc[i][1] + bb.y + x0 * wd0.y + x1 * wd1.y + x2 * wd2.y;
    r.z = acc[i][2] + bb.z + x0 * wd0.z + x1 * wd1.z + x2 * wd2.z;
    r.w = acc[i][3] + bb.w + x0 * wd0.w + x1 * wd1.w + x2 * wd2.w;
    *(float4*)&out[(size_t)ml * G + nbase] = r;
  }
}

// ---------------------------------------------------------------------------
// scan16: 16 groups x 4 batches x 16 slices (25 units) = 256 WGs, PLAIN
// launch (no cooperative API): 256 WGs x 7 waves x ~13KB LDS on 256 CUs is
// de-facto co-resident (HW fills every CU once before doubling up); the
// guard valve turns any residual scheduling pathology into a wrong answer,
// never a hang (1M polls ~ 40ms, latched once per launch).
// Thread (kh,ul,bi) computes all 4 gates over its k-quarter; k-reduce via
// part[][]. h crosses WGs as RELAXED AGENT-scope atomics (no invalidates ->
// weights stay L2-resident). gsb = steps completed in ALL prior scan
// launches (any layer); counter is globally monotone at +NSLICE/step.
// Within-launch spin only for tt>0; cross-launch deps are ordered by stream
// serialization. Per-layer hbuf/cbuf carry h/c across chunks; hbuf parity on
// layer-local absolute t.
// ---------------------------------------------------------------------------
__global__ __launch_bounds__(448) void scan16(const float* __restrict__ zx,   // [B][tcnt][G] chunk
                                              float* __restrict__ hck,        // [B][tcnt][U] chunk
                                              const float* __restrict__ WP,   // packed
                                              const float* __restrict__ pI,
                                              const float* __restrict__ pF,
                                              const float* __restrict__ pO,
                                              float* __restrict__ hbuf,       // [NG][2][BW][512] per-layer
                                              unsigned* __restrict__ ctr,     // [NG][32] shared
                                              float* __restrict__ cbuf,       // [B][400] per-layer
                                              unsigned gsb, int t0, int tcnt) {
  __shared__ __align__(16) float h_lds[BW * HPAD];
  __shared__ float part[4][4][UPS][BW];  // [gate][kh][ul][bi]
  const int g = blockIdx.x & (NGROUP - 1);
  const int s = blockIdx.x >> 4;
  const int tid = threadIdx.x;
  const bool act = tid < 400;
  const int kh = act ? (tid / 100) : 0;
  const int rem = act ? (tid % 100) : 0;
  const int ul = rem >> 2;      // 0..24
  const int bi = rem & 3;
  const bool cellth = tid < 100;
  const int ul_c = tid >> 2;    // cell: 0..24
  const int bi_c = tid & 3;
  float c = 0.f, pIv = 0.f, pFv = 0.f, pOv = 0.f;
  if (cellth) {
    pIv = pI[s * UPS + ul_c];
    pFv = pF[s * UPS + ul_c];
    pOv = pO[s * UPS + ul_c];
    if (t0 > 0) c = cbuf[(size_t)(g * BW + bi_c) * U + s * UPS + ul_c];
  }
  for (int i = tid; i < BW * HPAD; i += 448) h_lds[i] = 0.f;
  // weight pointers: float4 index = s*10000 + gate*2500 + kh*625 + j*25 + ul
  const float4* __restrict__ wb =
      (const float4*)WP + (size_t)s * 10000 + (size_t)kh * 625 + ul;
  const float4* __restrict__ w0 = wb;
  const float4* __restrict__ w1 = wb + 2500;
  const float4* __restrict__ w2 = wb + 5000;
  const float4* __restrict__ w3 = wb + 7500;
  const float4* __restrict__ hb4 =
      (const float4*)(h_lds + bi * HPAD) + kh * UPS;
  const float* __restrict__ zrow_c =
      cellth ? (zx + ((size_t)(g * BW + bi_c) * tcnt) * G + s * UPS + ul_c) : zx;
  float* hbg = hbuf + (size_t)g * 2 * BW * 512;
  unsigned* ctrb = ctr + g * 32;
  bool dead = false;  // tid 0 only
  __syncthreads();

  for (int tt = 0; tt < tcnt; ++tt) {
    const int t = t0 + tt;  // layer-local absolute step (hbuf parity)

    // zx prefetch (cell threads): independent of the h handshake.
    float z0 = 0.f, z1 = 0.f, z2 = 0.f, z3 = 0.f;
    if (cellth) {
      const float* zt = zrow_c + (size_t)tt * G;
      z0 = zt[0];
      z1 = zt[400];
      z2 = zt[800];
      z3 = zt[1200];
    }

    if (t > 0) {
      if (tt > 0) {  // cross-launch deps already complete (stream order)
        const unsigned target = (unsigned)NSLICE * (gsb + (unsigned)tt);
        if (tid == 0 && !dead) {
          int guard = 0;
          while (__hip_atomic_load(ctrb, __ATOMIC_RELAXED,
                                   __HIP_MEMORY_SCOPE_AGENT) < target) {
            if (++guard > 1000000) { dead = true; break; }  // anti-hang valve
          }
        }
      }
      __syncthreads();
      if (act) {
        // coherent (agent-scope, relaxed) reads: fresh without invalidates
        const int bi_s = tid / 100;   // 0..3
        const int k4_s = tid % 100;   // 0..99
        float* src = &hbg[(size_t)((t & 1) * BW + bi_s) * 512 + k4_s * 4];
        float4 v;
        v.x = __hip_atomic_load(src + 0, __ATOMIC_RELAXED, __HIP_MEMORY_SCOPE_AGENT);
        v.y = __hip_atomic_load(src + 1, __ATOMIC_RELAXED, __HIP_MEMORY_SCOPE_AGENT);
        v.z = __hip_atomic_load(src + 2, __ATOMIC_RELAXED, __HIP_MEMORY_SCOPE_AGENT);
        v.w = __hip_atomic_load(src + 3, __ATOMIC_RELAXED, __HIP_MEMORY_SCOPE_AGENT);
        *(float4*)&h_lds[bi_s * HPAD + k4_s * 4] = v;
      }
      __syncthreads();
    }

    if (act) {
      float p0 = 0.f, p1 = 0.f, p2 = 0.f, p3 = 0.f;
#pragma unroll 5
      for (int j = 0; j < UPS; ++j) {
        const float4 h4 = hb4[j];
        float4 w;
        w = w0[(size_t)j * 25];
        p0 += w.x * h4.x + w.y * h4.y + w.z * h4.z + w.w * h4.w;
        w = w1[(size_t)j * 25];
        p1 += w.x * h4.x + w.y * h4.y + w.z * h4.z + w.w * h4.w;
        w = w2[(size_t)j * 25];
        p2 += w.x * h4.x + w.y * h4.y + w.z * h4.z + w.w * h4.w;
        w = w3[(size_t)j * 25];
        p3 += w.x * h4.x + w.y * h4.y + w.z * h4.z + w.w * h4.w;
      }
      part[0][kh][ul][bi] = p0;
      part[1][kh][ul][bi] = p1;
      part[2][kh][ul][bi] = p2;
      part[3][kh][ul][bi] = p3;
    }
    __syncthreads();
    if (cellth) {
      const float zi = z0 + part[0][0][ul_c][bi_c] + part[0][1][ul_c][bi_c]
                     + part[0][2][ul_c][bi_c] + part[0][3][ul_c][bi_c] + pIv * c;
      const float zf = z1 + part[1][0][ul_c][bi_c] + part[1][1][ul_c][bi_c]
                     + part[1][2][ul_c][bi_c] + part[1][3][ul_c][bi_c] + pFv * c;
      const float zg = z2 + part[2][0][ul_c][bi_c] + part[2][1][ul_c][bi_c]
                     + part[2][2][ul_c][bi_c] + part[2][3][ul_c][bi_c];
      const float ig = 1.f / (1.f + expf(-zi));
      const float fg = 1.f / (1.f + expf(-zf));
      const float cn = fg * c + ig * tanhf(zg);
      const float zo = z3 + part[3][0][ul_c][bi_c] + part[3][1][ul_c][bi_c]
                     + part[3][2][ul_c][bi_c] + part[3][3][ul_c][bi_c] + pOv * cn;
      const float og = 1.f / (1.f + expf(-zo));
      const float hn = og * tanhf(cn);
      c = cn;
      hck[((size_t)(g * BW + bi_c) * tcnt + tt) * U + s * UPS + ul_c] = hn;
      // coherent store: goes to the coherence point, no L2 dirty state
      __hip_atomic_store(
          &hbg[(size_t)(((t + 1) & 1) * BW + bi_c) * 512 + s * UPS + ul_c], hn,
          __ATOMIC_RELAXED, __HIP_MEMORY_SCOPE_AGENT);
    }
    __threadfence();   // order h stores before the counter add
    __syncthreads();   // all stores drained before tid0's add
    if (tid == 0)
      __hip_atomic_fetch_add(ctrb, 1u, __ATOMIC_RELEASE,
                             __HIP_MEMORY_SCOPE_AGENT);
  }
  if (cellth) cbuf[(size_t)(g * BW + bi_c) * U + s * UPS + ul_c] = c;
}

// ---------------------------------------------------------------------------
// Head (chunked): y = h2c @ Wm + bm, activations. One WG per chunk row.
// ---------------------------------------------------------------------------
__global__ __launch_bounds__(128) void head_kernel(const float* __restrict__ h2c, // [B*tcnt][400] chunk
                                                   const float* __restrict__ Wm,  // [400][121]
                                                   const float* __restrict__ bm,  // [121]
                                                   float* __restrict__ out,       // [B*T][121] global
                                                   int t0, int tcnt) {
  __shared__ __align__(16) float hs[U];
  __shared__ float ys[MOUT];
  const int btl = blockIdx.x;
  const size_t bt = (size_t)(btl / tcnt) * TSTEPS + t0 + (btl % tcnt);
  const int j = threadIdx.x;
  for (int i = j; i < U / 4; i += 128) {
    ((float4*)hs)[i] = ((const float4*)(h2c + (size_t)btl * U))[i];
  }
  __syncthreads();
  if (j < MOUT) {
    float acc = bm[j];
#pragma unroll 4
    for (int k = 0; k < U; ++k) acc += hs[k] * Wm[k * MOUT + j];
    ys[j] = acc;
  }
  __syncthreads();
  if (j < MOUT) {
    float v;
    if (j == 0) {
      v = 1.f / (1.f + expf(-ys[0]));
    } else if (j < 21) {  // softmax over ys[1..20]
      float mx = -1e30f;
      for (int q = 1; q < 21; ++q) mx = fmaxf(mx, ys[q]);
      float sden = 0.f;
      for (int q = 1; q < 21; ++q) sden += expf(ys[q] - mx);
      v = expf(ys[j] - mx) / sden;
    } else if (j < 61) {  // mu1, mu2
      v = ys[j];
    } else if (j < 101) {  // s1, s2
      v = expf(ys[j]);
    } else {  // rho
      v = tanhf(ys[j]);
    }
    out[bt * MOUT + j] = v;
  }
}

// ---------------------------------------------------------------------------
// Launch. Layer-interleaved chunk pipeline; tcnt = largest candidate whose
// footprint fits ws_size:
//   tcnt=1200 -> ~860MB  600 -> ~438MB  400 -> ~296MB  240 -> ~181MB
//   120 -> ~95MB  80 -> ~66MB  48 -> ~43MB  24 -> ~26MB  8 -> ~14.5MB
//   4 -> ~12.5MB  2 -> ~11.5MB
// All launches are plain <<<>>> (no cooperative API, no capture queries).
// ---------------------------------------------------------------------------
extern "C" void kernel_launch(void* const* d_in, const int* in_sizes, int n_in,
                              void* d_out, int out_size, void* d_ws, size_t ws_size,
                              hipStream_t stream) {
  const float* inputs = (const float*)d_in[0];
  const float* Wx0 = (const float*)d_in[1];
  const float* Wh0 = (const float*)d_in[2];
  const float* b0 = (const float*)d_in[3];
  const float* pI0 = (const float*)d_in[4];
  const float* pF0 = (const float*)d_in[5];
  const float* pO0 = (const float*)d_in[6];
  const float* Wx1 = (const float*)d_in[7];
  const float* Wh1 = (const float*)d_in[8];
  const float* b1 = (const float*)d_in[9];
  const float* pI1 = (const float*)d_in[10];
  const float* pF1 = (const float*)d_in[11];
  const float* pO1 = (const float*)d_in[12];
  const float* Wx2 = (const float*)d_in[13];
  const float* Wh2 = (const float*)d_in[14];
  const float* b2 = (const float*)d_in[15];
  const float* pI2 = (const float*)d_in[16];
  const float* pF2 = (const float*)d_in[17];
  const float* pO2 = (const float*)d_in[18];
  const float* Wm = (const float*)d_in[19];
  const float* bm = (const float*)d_in[20];
  float* out = (float*)d_out;

  const size_t WP_SZ = (size_t)G * U;        // 640,000 floats / layer
  const size_t HBUF_SZ = (size_t)NGROUP * 2 * BW * 512;  // 65,536 floats
  const size_t CBUF_SZ = (size_t)BATCH * U;              // 25,600 floats
  const size_t CTR_BYTES = (size_t)NGROUP * 32 * sizeof(unsigned);

  // pick largest tcnt that fits (all divide 1200, all even)
  const int cands[11] = {1200, 600, 400, 240, 120, 80, 48, 24, 8, 4, 2};
  int tcnt = 2;
  for (int ci = 0; ci < 11; ++ci) {
    const size_t tc = (size_t)cands[ci];
    const size_t zxc = (size_t)BATCH * tc * G;
    const size_t hc = (size_t)BATCH * tc * U;
    const size_t need =
        (3 * WP_SZ + zxc + 3 * hc + 3 * HBUF_SZ + 3 * CBUF_SZ) * sizeof(float)
        + CTR_BYTES + 256;
    if (need <= ws_size) { tcnt = cands[ci]; break; }
  }
  const int nchunk = TSTEPS / tcnt;

  // workspace layout (floats)
  float* ws = (float*)d_ws;
  float* wp0 = ws;
  float* wp1 = wp0 + WP_SZ;
  float* wp2 = wp1 + WP_SZ;
  float* ZX = wp2 + WP_SZ;                        // B*tcnt*G
  float* H0 = ZX + (size_t)BATCH * tcnt * G;      // B*tcnt*U
  float* H1 = H0 + (size_t)BATCH * tcnt * U;
  float* H2 = H1 + (size_t)BATCH * tcnt * U;
  float* hbuf0 = H2 + (size_t)BATCH * tcnt * U;   // per-layer handshake bufs
  float* hbuf1 = hbuf0 + HBUF_SZ;
  float* hbuf2 = hbuf1 + HBUF_SZ;
  float* cbuf0 = hbuf2 + HBUF_SZ;                 // per-layer c carry
  float* cbuf1 = cbuf0 + CBUF_SZ;
  float* cbuf2 = cbuf1 + CBUF_SZ;
  unsigned* ctr = (unsigned*)(cbuf2 + CBUF_SZ);   // shared monotone counters

  hipMemsetAsync(ctr, 0, CTR_BYTES, stream);

  pack_w16<<<625, 256, 0, stream>>>(Wh0, wp0);
  pack_w16<<<625, 256, 0, stream>>>(Wh1, wp1);
  pack_w16<<<625, 256, 0, stream>>>(Wh2, wp2);

  const int gemm_gy = (BATCH * tcnt) / 128;  // tcnt even -> integer
  unsigned gsb = 0;                          // global steps before next scan

  for (int ch = 0; ch < nchunk; ++ch) {
    const int t0 = ch * tcnt;
    // layer 0
    zx0_kernel<<<2048, 256, 0, stream>>>(inputs, Wx0, b0, ZX, t0, tcnt);
    scan16<<<dim3(256), dim3(448), 0, stream>>>(ZX, H0, wp0, pI0, pF0, pO0,
                                                hbuf0, ctr, cbuf0, gsb, t0, tcnt);
    gsb += (unsigned)tcnt;
    // layer 1
    zx_gemm2<<<dim3(25, gemm_gy), 256, 0, stream>>>(H0, inputs, Wx1, b1, ZX, t0, tcnt);
    scan16<<<dim3(256), dim3(448), 0, stream>>>(ZX, H1, wp1, pI1, pF1, pO1,
                                                hbuf1, ctr, cbuf1, gsb, t0, tcnt);
    gsb += (unsigned)tcnt;
    // layer 2
    zx_gemm2<<<dim3(25, gemm_gy), 256, 0, stream>>>(H1, inputs, Wx2, b2, ZX, t0, tcnt);
    scan16<<<dim3(256), dim3(448), 0, stream>>>(ZX, H2, wp2, pI2, pF2, pO2,
                                                hbuf2, ctr, cbuf2, gsb, t0, tcnt);
    gsb += (unsigned)tcnt;
    // head for this chunk
    head_kernel<<<BATCH * tcnt, 128, 0, stream>>>(H2, Wm, bm, out, t0, tcnt);
  }
}